// Round 6
// baseline (794.040 us; speedup 1.0000x reference)
//
#include <hip/hip_runtime.h>
#include <math.h>

#define NPIX 524288   // 8*256*256

typedef __attribute__((ext_vector_type(8))) short short8b;
typedef __attribute__((ext_vector_type(4))) float f32x4;
#define MFMA16 __builtin_amdgcn_mfma_f32_16x16x32_bf16

__device__ inline unsigned short bf16_rn(float x) {
    unsigned u = __float_as_uint(x);
    unsigned r = (u + 0x7FFFu + ((u >> 16) & 1u)) >> 16;
    return (unsigned short)r;
}
__device__ inline float bf16_f(unsigned short h) {
    return __uint_as_float(((unsigned)h) << 16);
}
__device__ inline void split4(float a, float b, float c, float d, ushort4& hv, ushort4& lv) {
    hv.x = bf16_rn(a); lv.x = bf16_rn(a - bf16_f(hv.x));
    hv.y = bf16_rn(b); lv.y = bf16_rn(b - bf16_f(hv.y));
    hv.z = bf16_rn(c); lv.z = bf16_rn(c - bf16_f(hv.z));
    hv.w = bf16_rn(d); lv.w = bf16_rn(d - bf16_f(hv.w));
}

// ---------- kernel 1a: collapse offset head: Wcomb[p][cin][tap] = sum_c Woff2[p,c]*Woff1[c,cin,tap]
__global__ void build_wcomb_kernel(const float* __restrict__ Woff1,
                                   const float* __restrict__ boff1,
                                   const float* __restrict__ Woff2,
                                   float* __restrict__ wcomb,
                                   float* __restrict__ bcomb) {
    int idx = blockIdx.x * 256 + threadIdx.x;
    if (idx < 2 * 64 * 25) {
        int p = idx / 1600;
        int rest = idx - p * 1600;
        float s = 0.f;
        for (int cm = 0; cm < 64; ++cm)
            s += Woff2[p * 64 + cm] * Woff1[cm * 1600 + rest];
        wcomb[idx] = s;
    }
    if (idx < 2) {
        float s = 0.f;
        for (int cm = 0; cm < 64; ++cm) s += Woff2[idx * 64 + cm] * boff1[cm];
        bcomb[idx] = s;
    }
}

// ---------- kernel 1b: Wcat[128][64] = [Wq ; Wproj@Wq ; 0] as bf16 hi/lo planes + fp32 bcat
__global__ void build_wcat_kernel(const float* __restrict__ Wq, const float* __restrict__ bq,
                                  const float* __restrict__ wcomb,
                                  unsigned short* __restrict__ wcath,
                                  unsigned short* __restrict__ wcatl,
                                  float* __restrict__ bcat) {
    int idx = blockIdx.x * 256 + threadIdx.x;
    if (idx < 8192) {
        int r = idx >> 6, c = idx & 63;
        float v = 0.f;
        if (r < 64) v = Wq[r * 64 + c];
        else if (r < 114) {
            int ch = r - 64, p = ch / 25, tap = ch % 25;
            for (int cin = 0; cin < 64; ++cin)
                v += wcomb[p * 1600 + cin * 25 + tap] * Wq[cin * 64 + c];
        }
        unsigned short hh = bf16_rn(v);
        wcath[idx] = hh;
        wcatl[idx] = bf16_rn(v - bf16_f(hh));
    }
    if (idx >= 8192 && idx < 8192 + 128) {
        int r = idx - 8192;
        float v = 0.f;
        if (r < 64) v = bq[r];
        else if (r < 114) {
            int ch = r - 64, p = ch / 25, tap = ch % 25;
            for (int cin = 0; cin < 64; ++cin)
                v += wcomb[p * 1600 + cin * 25 + tap] * bq[cin];
        }
        bcat[r] = v;
    }
}

// ---------- kernel 1c: fixed weights -> bf16 hi/lo planes (wkv rows 0..63=k, 64..127=v; wout)
__global__ void build_wfixed_kernel(const float* __restrict__ Wk, const float* __restrict__ Wv,
                                    const float* __restrict__ Wout,
                                    unsigned short* __restrict__ wkvh, unsigned short* __restrict__ wkvl,
                                    unsigned short* __restrict__ wouth, unsigned short* __restrict__ woutl) {
    int idx = blockIdx.x * 256 + threadIdx.x;
    if (idx < 8192) {
        float v = (idx < 4096) ? Wk[idx] : Wv[idx - 4096];
        unsigned short hh = bf16_rn(v);
        wkvh[idx] = hh;
        wkvl[idx] = bf16_rn(v - bf16_f(hh));
    } else if (idx < 12288) {
        float v = Wout[idx - 8192];
        unsigned short hh = bf16_rn(v);
        wouth[idx - 8192] = hh;
        woutl[idx - 8192] = bf16_rn(v - bf16_f(hh));
    }
}

// ---------- kernel 2: fused q + proj conv via MFMA (M=64 pixels, N=128, K=64)
__global__ __launch_bounds__(256)
void convqp_kernel(const float* __restrict__ in, const unsigned short* __restrict__ wh,
                   const unsigned short* __restrict__ wl, const float* __restrict__ bcat,
                   float* __restrict__ qout, float* __restrict__ projout) {
    __shared__ unsigned short a_hi[64 * 72], a_lo[64 * 72];
    int t = threadIdx.x;
    int p = t & 63, w = t >> 6;
    int pix0 = blockIdx.x * 64;
    {
        const float4* src = (const float4*)(in + (size_t)(pix0 + p) * 64 + w * 16);
#pragma unroll
        for (int u4 = 0; u4 < 4; ++u4) {
            float4 v = src[u4];
            ushort4 hv, lv;
            split4(v.x, v.y, v.z, v.w, hv, lv);
            *(ushort4*)&a_hi[p * 72 + w * 16 + u4 * 4] = hv;
            *(ushort4*)&a_lo[p * 72 + w * 16 + u4 * 4] = lv;
        }
    }
    __syncthreads();
    int lrow = t & 15, lgrp = (t & 63) >> 4;
    int wc = w * 32;
    f32x4 acc[4][2];
#pragma unroll
    for (int mi = 0; mi < 4; ++mi)
#pragma unroll
        for (int nj = 0; nj < 2; ++nj) acc[mi][nj] = (f32x4){0.f, 0.f, 0.f, 0.f};
#pragma unroll
    for (int dk = 0; dk < 2; ++dk) {
        int k0 = dk * 32 + lgrp * 8;
        short8b bh[2], bl[2];
#pragma unroll
        for (int nj = 0; nj < 2; ++nj) {
            int c = wc + nj * 16 + lrow;
            bh[nj] = *(const short8b*)(wh + c * 64 + k0);
            bl[nj] = *(const short8b*)(wl + c * 64 + k0);
        }
#pragma unroll
        for (int mi = 0; mi < 4; ++mi) {
            int r = mi * 16 + lrow;
            short8b ah = *(short8b*)&a_hi[r * 72 + k0];
            short8b al = *(short8b*)&a_lo[r * 72 + k0];
#pragma unroll
            for (int nj = 0; nj < 2; ++nj) {
                acc[mi][nj] = MFMA16(ah, bh[nj], acc[mi][nj], 0, 0, 0);
                acc[mi][nj] = MFMA16(ah, bl[nj], acc[mi][nj], 0, 0, 0);
                acc[mi][nj] = MFMA16(al, bh[nj], acc[mi][nj], 0, 0, 0);
            }
        }
    }
    int b = pix0 >> 16, hw0 = pix0 & 65535;
#pragma unroll
    for (int nj = 0; nj < 2; ++nj) {
        int c = wc + nj * 16 + lrow;
        if (c < 114) {
            float bias = bcat[c];
            float* dst = (c < 64) ? (qout + (((size_t)(b * 64 + c)) << 16) + hw0)
                                  : (projout + (((size_t)(b * 50 + (c - 64))) << 16) + hw0);
#pragma unroll
            for (int mi = 0; mi < 4; ++mi) {
                float4 o;
                o.x = acc[mi][nj][0] + bias;
                o.y = acc[mi][nj][1] + bias;
                o.z = acc[mi][nj][2] + bias;
                o.w = acc[mi][nj][3] + bias;
                *(float4*)(dst + mi * 16 + lgrp * 4) = o;
            }
        }
    }
}

// ---------- kernel 3: offset via 25-tap shift-add over proj planes -> sample coords
__global__ __launch_bounds__(256)
void offset_gather_kernel(const float* __restrict__ proj, const float* __restrict__ bcomb,
                          float2* __restrict__ coords) {
    int x = threadIdx.x, y = blockIdx.x, b = blockIdx.y;
    const float* pb = proj + (((size_t)b * 50) << 16);
    float a0 = bcomb[0], a1 = bcomb[1];
#pragma unroll
    for (int ky = 0; ky < 5; ++ky) {
        int yy = y + ky - 2;
        if (yy < 0 || yy >= 256) continue;
#pragma unroll
        for (int kx = 0; kx < 5; ++kx) {
            int xx = x + kx - 2;
            if (xx < 0 || xx >= 256) continue;
            int tap = ky * 5 + kx;
            size_t off = (size_t)yy * 256 + xx;
            a0 += pb[((size_t)tap << 16) + off];
            a1 += pb[((size_t)(25 + tap) << 16) + off];
        }
    }
    float ox = tanhf(a0) * 5.f, oy = tanhf(a1) * 5.f;
    float vgx = (float)x + ox, vgy = (float)y + oy;
    float ix = vgx * (256.f / 255.f) - 0.5f;
    float iy = vgy * (256.f / 255.f) - 0.5f;
    coords[(((size_t)b) << 16) + y * 256 + x] = make_float2(ix, iy);
}

// ---------- kernel 4: bilinear sample + k/v convs via MFMA, emit bf16 hi/lo planes
__global__ __launch_bounds__(256)
void sample_kv_kernel(const float* __restrict__ x, const float2* __restrict__ coords,
                      const unsigned short* __restrict__ wh, const unsigned short* __restrict__ wl,
                      const float* __restrict__ bk, const float* __restrict__ bv,
                      const float* __restrict__ rpb,
                      unsigned short* __restrict__ khi, unsigned short* __restrict__ klo,
                      unsigned short* __restrict__ vhi, unsigned short* __restrict__ vlo) {
    __shared__ unsigned short a_hi[64 * 72], a_lo[64 * 72];
    int t = threadIdx.x;
    int p = t & 63, w = t >> 6;
    int pix0 = blockIdx.x * 64;
    int pix = pix0 + p;
    int b = pix0 >> 16, hw0 = pix0 & 65535, h = hw0 >> 8;
    {
        float2 cc = coords[pix];
        float ix0f = floorf(cc.x), iy0f = floorf(cc.y);
        float wx1 = cc.x - ix0f, wy1 = cc.y - iy0f;
        float wx0 = 1.f - wx1, wy0 = 1.f - wy1;
        int ix0 = (int)ix0f, iy0 = (int)iy0f;
        float s[16];
#pragma unroll
        for (int u = 0; u < 16; ++u) s[u] = 0.f;
        const float* xb = x + (((size_t)b) << 16) * 64 + w * 16;
        int cxs[4] = {ix0, ix0 + 1, ix0, ix0 + 1};
        int cys[4] = {iy0, iy0, iy0 + 1, iy0 + 1};
        float ws4[4] = {wx0 * wy0, wx1 * wy0, wx0 * wy1, wx1 * wy1};
#pragma unroll
        for (int cr = 0; cr < 4; ++cr) {
            int cx = cxs[cr], cy = cys[cr];
            if (cx >= 0 && cx < 256 && cy >= 0 && cy < 256) {
                float wgt = ws4[cr];
                const float4* sp = (const float4*)(xb + ((size_t)(cy * 256 + cx) << 6));
#pragma unroll
                for (int q4 = 0; q4 < 4; ++q4) {
                    float4 v = sp[q4];
                    s[4 * q4] += wgt * v.x; s[4 * q4 + 1] += wgt * v.y;
                    s[4 * q4 + 2] += wgt * v.z; s[4 * q4 + 3] += wgt * v.w;
                }
            }
        }
#pragma unroll
        for (int u4 = 0; u4 < 4; ++u4) {
            ushort4 hv, lv;
            split4(s[u4 * 4], s[u4 * 4 + 1], s[u4 * 4 + 2], s[u4 * 4 + 3], hv, lv);
            *(ushort4*)&a_hi[p * 72 + w * 16 + u4 * 4] = hv;
            *(ushort4*)&a_lo[p * 72 + w * 16 + u4 * 4] = lv;
        }
    }
    __syncthreads();
    int lrow = t & 15, lgrp = (t & 63) >> 4;
    int wc = w * 32;
    f32x4 acc[4][2];
#pragma unroll
    for (int mi = 0; mi < 4; ++mi)
#pragma unroll
        for (int nj = 0; nj < 2; ++nj) acc[mi][nj] = (f32x4){0.f, 0.f, 0.f, 0.f};
#pragma unroll
    for (int dk = 0; dk < 2; ++dk) {
        int k0 = dk * 32 + lgrp * 8;
        short8b bh[2], bl[2];
#pragma unroll
        for (int nj = 0; nj < 2; ++nj) {
            int c = wc + nj * 16 + lrow;
            bh[nj] = *(const short8b*)(wh + c * 64 + k0);
            bl[nj] = *(const short8b*)(wl + c * 64 + k0);
        }
#pragma unroll
        for (int mi = 0; mi < 4; ++mi) {
            int r = mi * 16 + lrow;
            short8b ah = *(short8b*)&a_hi[r * 72 + k0];
            short8b al = *(short8b*)&a_lo[r * 72 + k0];
#pragma unroll
            for (int nj = 0; nj < 2; ++nj) {
                acc[mi][nj] = MFMA16(ah, bh[nj], acc[mi][nj], 0, 0, 0);
                acc[mi][nj] = MFMA16(ah, bl[nj], acc[mi][nj], 0, 0, 0);
                acc[mi][nj] = MFMA16(al, bh[nj], acc[mi][nj], 0, 0, 0);
            }
        }
    }
#pragma unroll
    for (int nj = 0; nj < 2; ++nj) {
        int c = wc + nj * 16 + lrow;
        float bias;
        unsigned short *dh, *dl;
        if (c < 64) { bias = bk[c]; dh = khi; dl = klo; }
        else        { bias = bv[c - 64] + rpb[(c - 64) * 256 + h]; dh = vhi; dl = vlo; }
        size_t o = (((size_t)(b * 64 + (c & 63))) << 16) + hw0;
#pragma unroll
        for (int mi = 0; mi < 4; ++mi) {
            float v0 = acc[mi][nj][0] + bias;
            float v1 = acc[mi][nj][1] + bias;
            float v2 = acc[mi][nj][2] + bias;
            float v3 = acc[mi][nj][3] + bias;
            ushort4 hv, lv;
            split4(v0, v1, v2, v3, hv, lv);
            *(ushort4*)(dh + o + mi * 16 + lgrp * 4) = hv;
            *(ushort4*)(dl + o + mi * 16 + lgrp * 4) = lv;
        }
    }
}

// ---------- kernel 4b: in-place paired-tile transpose of v hi/lo planes ([head][j][d] -> [head][d][j])
__global__ __launch_bounds__(256)
void vtrans_kernel(unsigned short* __restrict__ vhi, unsigned short* __restrict__ vlo) {
    __shared__ unsigned short T1[64][72];
    __shared__ unsigned short T2[64][72];
    const int ti_tab[10] = {0, 0, 0, 0, 1, 1, 1, 2, 2, 3};
    const int tj_tab[10] = {0, 1, 2, 3, 1, 2, 3, 2, 3, 3};
    int head = blockIdx.x / 10, pidx = blockIdx.x - head * 10;
    int ti = ti_tab[pidx], tj = tj_tab[pidx];
    int t = threadIdx.x;
    int r = t >> 2, cs = (t & 3) * 16;
    bool diag = (ti == tj);
#pragma unroll
    for (int pl = 0; pl < 2; ++pl) {
        unsigned short* base = (pl ? vlo : vhi) + ((size_t)head << 16);
        *(short8b*)&T1[r][cs]     = *(const short8b*)(base + (size_t)(ti * 64 + r) * 256 + tj * 64 + cs);
        *(short8b*)&T1[r][cs + 8] = *(const short8b*)(base + (size_t)(ti * 64 + r) * 256 + tj * 64 + cs + 8);
        if (!diag) {
            *(short8b*)&T2[r][cs]     = *(const short8b*)(base + (size_t)(tj * 64 + r) * 256 + ti * 64 + cs);
            *(short8b*)&T2[r][cs + 8] = *(const short8b*)(base + (size_t)(tj * 64 + r) * 256 + ti * 64 + cs + 8);
        }
        __syncthreads();
        {
            short8b o0, o1;
#pragma unroll
            for (int u = 0; u < 8; ++u) { o0[u] = (short)T1[cs + u][r]; o1[u] = (short)T1[cs + 8 + u][r]; }
            *(short8b*)(base + (size_t)(tj * 64 + r) * 256 + ti * 64 + cs) = o0;
            *(short8b*)(base + (size_t)(tj * 64 + r) * 256 + ti * 64 + cs + 8) = o1;
            if (!diag) {
#pragma unroll
                for (int u = 0; u < 8; ++u) { o0[u] = (short)T2[cs + u][r]; o1[u] = (short)T2[cs + 8 + u][r]; }
                *(short8b*)(base + (size_t)(ti * 64 + r) * 256 + tj * 64 + cs) = o0;
                *(short8b*)(base + (size_t)(ti * 64 + r) * 256 + tj * 64 + cs + 8) = o1;
            }
        }
        __syncthreads();
    }
}

// ---------- kernel 5: MFMA attention; k/v fragments from global, software-pipelined (3-buf, depth-2)
__global__ __launch_bounds__(512, 4)
void attn_mfma_kernel(float* __restrict__ qo,
                      const unsigned short* __restrict__ khig, const unsigned short* __restrict__ klog,
                      const unsigned short* __restrict__ vthig, const unsigned short* __restrict__ vtlog) {
    __shared__ char sm[71680];
    unsigned short* qhi = (unsigned short*)sm;
    unsigned short* qlo = (unsigned short*)(sm + 33792);
    unsigned short* phi = (unsigned short*)sm;
    unsigned short* plo = (unsigned short*)(sm + 33792);
    float* ost = (float*)sm;
    float* redm = (float*)(sm + 67584);
    float* reds = (float*)(sm + 69632);

    int t = threadIdx.x;
    int lane = t & 63, w = t >> 6;
    int lrow = lane & 15, lgrp = lane >> 4;
    int wc = w * 32;

    int bid = blockIdx.x;
    int xcd = bid & 7, r = bid >> 3;
    int head = xcd * 64 + (r >> 2), rt = r & 3;
    float* qg = qo + ((size_t)head << 16) + rt * 64 * 256;
    const unsigned short* kh = khig + ((size_t)head << 16);
    const unsigned short* kl = klog + ((size_t)head << 16);
    const unsigned short* vth = vthig + ((size_t)head << 16);
    const unsigned short* vtl = vtlog + ((size_t)head << 16);

    // k-fragment pipeline buffers: step s covers k0 = s*32 + lgrp*8, s = 0..7
    short8b kbh[3][2], kbl[3][2];
    // prologue: issue steps 0,1 BEFORE q staging (latency hides under staging+barrier)
#pragma unroll
    for (int s = 0; s < 2; ++s)
#pragma unroll
        for (int nj = 0; nj < 2; ++nj) {
            size_t go = (size_t)(wc + nj * 16 + lrow) * 256 + s * 32 + lgrp * 8;
            kbh[s][nj] = *(const short8b*)(kh + go);
            kbl[s][nj] = *(const short8b*)(kl + go);
        }

    // ---- stage q 64x256 fp32 -> bf16 hi/lo in LDS
    {
        int row = t >> 3, cb = (t & 7) * 32;
        const float* qrow = qg + row * 256 + cb;
#pragma unroll
        for (int q4 = 0; q4 < 8; ++q4) {
            float4 v = *(const float4*)(qrow + q4 * 4);
            ushort4 hv, lv;
            split4(v.x, v.y, v.z, v.w, hv, lv);
            *(ushort4*)&qhi[row * 264 + cb + q4 * 4] = hv;
            *(ushort4*)&qlo[row * 264 + cb + q4 * 4] = lv;
        }
    }
    __syncthreads();

    f32x4 acc[4][2];
#pragma unroll
    for (int mi = 0; mi < 4; ++mi)
#pragma unroll
        for (int nj = 0; nj < 2; ++nj) acc[mi][nj] = (f32x4){0.f, 0.f, 0.f, 0.f};

    // ---- phase 1: S = q k^T, 8 steps, depth-2 prefetch
#pragma unroll
    for (int s = 0; s < 8; ++s) {
        if (s < 6) {
            int sp = s + 2, bp = sp % 3;
#pragma unroll
            for (int nj = 0; nj < 2; ++nj) {
                size_t go = (size_t)(wc + nj * 16 + lrow) * 256 + sp * 32 + lgrp * 8;
                kbh[bp][nj] = *(const short8b*)(kh + go);
                kbl[bp][nj] = *(const short8b*)(kl + go);
            }
        }
        int k0 = s * 32 + lgrp * 8, bc = s % 3;
        __builtin_amdgcn_s_setprio(1);
#pragma unroll
        for (int mi = 0; mi < 4; ++mi) {
            short8b ah = *(short8b*)&qhi[(mi * 16 + lrow) * 264 + k0];
            short8b al = *(short8b*)&qlo[(mi * 16 + lrow) * 264 + k0];
#pragma unroll
            for (int nj = 0; nj < 2; ++nj) {
                acc[mi][nj] = MFMA16(ah, kbh[bc][nj], acc[mi][nj], 0, 0, 0);
                acc[mi][nj] = MFMA16(ah, kbl[bc][nj], acc[mi][nj], 0, 0, 0);
                acc[mi][nj] = MFMA16(al, kbh[bc][nj], acc[mi][nj], 0, 0, 0);
            }
        }
        __builtin_amdgcn_s_setprio(0);
    }

    // v-fragment pipeline buffers; issue jc=0,1 now (latency hides under softmax)
    short8b vbh[3][2], vbl[3][2];
#pragma unroll
    for (int s = 0; s < 2; ++s)
#pragma unroll
        for (int nd = 0; nd < 2; ++nd) {
            size_t go = (size_t)(wc + nd * 16 + lrow) * 256 + s * 32 + lgrp * 8;
            vbh[s][nd] = *(const short8b*)(vth + go);
            vbl[s][nd] = *(const short8b*)(vtl + go);
        }

    // ---- phase 2: softmax
#pragma unroll
    for (int mi = 0; mi < 4; ++mi)
#pragma unroll
        for (int nj = 0; nj < 2; ++nj) acc[mi][nj] *= 0.125f;

    float mx[4][4];
#pragma unroll
    for (int mi = 0; mi < 4; ++mi)
#pragma unroll
        for (int rr = 0; rr < 4; ++rr) {
            float m = fmaxf(acc[mi][0][rr], acc[mi][1][rr]);
            m = fmaxf(m, __shfl_xor(m, 1));
            m = fmaxf(m, __shfl_xor(m, 2));
            m = fmaxf(m, __shfl_xor(m, 4));
            m = fmaxf(m, __shfl_xor(m, 8));
            mx[mi][rr] = m;
        }
    if (lrow == 0) {
#pragma unroll
        for (int mi = 0; mi < 4; ++mi)
#pragma unroll
            for (int rr = 0; rr < 4; ++rr)
                redm[w * 64 + mi * 16 + lgrp * 4 + rr] = mx[mi][rr];
    }
    __syncthreads();   // redm ready; all q-frag reads done -> phi/plo may overwrite
    float invl[4][4];
#pragma unroll
    for (int mi = 0; mi < 4; ++mi)
#pragma unroll
        for (int rr = 0; rr < 4; ++rr) {
            int row = mi * 16 + lgrp * 4 + rr;
            float m = redm[row];
#pragma unroll
            for (int ww = 1; ww < 8; ++ww) m = fmaxf(m, redm[ww * 64 + row]);
            float p0 = __expf(acc[mi][0][rr] - m);
            float p1 = __expf(acc[mi][1][rr] - m);
            unsigned short h0 = bf16_rn(p0), h1 = bf16_rn(p1);
            phi[row * 264 + wc + lrow] = h0;
            phi[row * 264 + wc + 16 + lrow] = h1;
            plo[row * 264 + wc + lrow] = bf16_rn(p0 - bf16_f(h0));
            plo[row * 264 + wc + 16 + lrow] = bf16_rn(p1 - bf16_f(h1));
            float ls = p0 + p1;
            ls += __shfl_xor(ls, 1);
            ls += __shfl_xor(ls, 2);
            ls += __shfl_xor(ls, 4);
            ls += __shfl_xor(ls, 8);
            if (lrow == 0) reds[w * 64 + row] = ls;
        }
    __syncthreads();   // phi/plo + reds ready
#pragma unroll
    for (int mi = 0; mi < 4; ++mi)
#pragma unroll
        for (int rr = 0; rr < 4; ++rr) {
            int row = mi * 16 + lgrp * 4 + rr;
            float l = 0.f;
#pragma unroll
            for (int ww = 0; ww < 8; ++ww) l += reds[ww * 64 + row];
            invl[mi][rr] = 1.f / l;
        }

    // ---- phase 3: O = P V, 8 steps, depth-2 prefetch
#pragma unroll
    for (int mi = 0; mi < 4; ++mi)
#pragma unroll
        for (int nd = 0; nd < 2; ++nd) acc[mi][nd] = (f32x4){0.f, 0.f, 0.f, 0.f};

#pragma unroll
    for (int jc = 0; jc < 8; ++jc) {
        if (jc < 6) {
            int jp = jc + 2, bp = jp % 3;
#pragma unroll
            for (int nd = 0; nd < 2; ++nd) {
                size_t go = (size_t)(wc + nd * 16 + lrow) * 256 + jp * 32 + lgrp * 8;
                vbh[bp][nd] = *(const short8b*)(vth + go);
                vbl[bp][nd] = *(const short8b*)(vtl + go);
            }
        }
        int j0 = jc * 32 + lgrp * 8, bc = jc % 3;
        __builtin_amdgcn_s_setprio(1);
#pragma unroll
        for (int mi = 0; mi < 4; ++mi) {
            short8b pa = *(short8b*)&phi[(mi * 16 + lrow) * 264 + j0];
            short8b pb = *(short8b*)&plo[(mi * 16 + lrow) * 264 + j0];
#pragma unroll
            for (int nd = 0; nd < 2; ++nd) {
                acc[mi][nd] = MFMA16(pa, vbh[bc][nd], acc[mi][nd], 0, 0, 0);
                acc[mi][nd] = MFMA16(pa, vbl[bc][nd], acc[mi][nd], 0, 0, 0);
                acc[mi][nd] = MFMA16(pb, vbh[bc][nd], acc[mi][nd], 0, 0, 0);
            }
        }
        __builtin_amdgcn_s_setprio(0);
    }
    __syncthreads();   // all phi/plo reads done -> ost may overwrite

    // ---- epilogue
#pragma unroll
    for (int mi = 0; mi < 4; ++mi)
#pragma unroll
        for (int nd = 0; nd < 2; ++nd)
#pragma unroll
            for (int rr = 0; rr < 4; ++rr)
                ost[(mi * 16 + lgrp * 4 + rr) * 260 + wc + nd * 16 + lrow] =
                    acc[mi][nd][rr] * invl[mi][rr];
    __syncthreads();
#pragma unroll
    for (int it = 0; it < 8; ++it) {
        int id = it * 512 + t;
        int row = id >> 6, col4 = (id & 63) * 4;
        float4 vv = *(float4*)&ost[row * 260 + col4];
        *(float4*)(qg + row * 256 + col4) = vv;
    }
}

// ---------- kernel 6: final 1x1 conv via MFMA (flat [pix][64] in/out, M=64, N=64, K=64)
__global__ __launch_bounds__(256)
void convout_kernel(const float* __restrict__ in, const unsigned short* __restrict__ wh,
                    const unsigned short* __restrict__ wl, const float* __restrict__ bias,
                    float* __restrict__ out) {
    __shared__ unsigned short a_hi[64 * 72], a_lo[64 * 72];
    int t = threadIdx.x;
    int p = t & 63, w = t >> 6;
    int pix0 = blockIdx.x * 64;
    {
        const float4* src = (const float4*)(in + (size_t)(pix0 + p) * 64 + w * 16);
#pragma unroll
        for (int u4 = 0; u4 < 4; ++u4) {
            float4 v = src[u4];
            ushort4 hv, lv;
            split4(v.x, v.y, v.z, v.w, hv, lv);
            *(ushort4*)&a_hi[p * 72 + w * 16 + u4 * 4] = hv;
            *(ushort4*)&a_lo[p * 72 + w * 16 + u4 * 4] = lv;
        }
    }
    __syncthreads();
    int lrow = t & 15, lgrp = (t & 63) >> 4;
    int c = w * 16 + lrow;
    f32x4 acc[4];
#pragma unroll
    for (int mi = 0; mi < 4; ++mi) acc[mi] = (f32x4){0.f, 0.f, 0.f, 0.f};
#pragma unroll
    for (int dk = 0; dk < 2; ++dk) {
        int k0 = dk * 32 + lgrp * 8;
        short8b bh = *(const short8b*)(wh + c * 64 + k0);
        short8b bl = *(const short8b*)(wl + c * 64 + k0);
#pragma unroll
        for (int mi = 0; mi < 4; ++mi) {
            int r = mi * 16 + lrow;
            short8b ah = *(short8b*)&a_hi[r * 72 + k0];
            short8b al = *(short8b*)&a_lo[r * 72 + k0];
            acc[mi] = MFMA16(ah, bh, acc[mi], 0, 0, 0);
            acc[mi] = MFMA16(ah, bl, acc[mi], 0, 0, 0);
            acc[mi] = MFMA16(al, bh, acc[mi], 0, 0, 0);
        }
    }
    float bb = bias[c];
#pragma unroll
    for (int mi = 0; mi < 4; ++mi) {
        int px0 = pix0 + mi * 16 + lgrp * 4;
#pragma unroll
        for (int rr = 0; rr < 4; ++rr)
            out[(size_t)(px0 + rr) * 64 + c] = acc[mi][rr] + bb;
    }
}

extern "C" void kernel_launch(void* const* d_in, const int* in_sizes, int n_in,
                              void* d_out, int out_size, void* d_ws, size_t ws_size,
                              hipStream_t stream) {
    const float* x     = (const float*)d_in[0];
    const float* Wq    = (const float*)d_in[1];
    const float* bq    = (const float*)d_in[2];
    const float* Wk    = (const float*)d_in[3];
    const float* bk    = (const float*)d_in[4];
    const float* Wv    = (const float*)d_in[5];
    const float* bv    = (const float*)d_in[6];
    const float* Woff1 = (const float*)d_in[7];
    const float* boff1 = (const float*)d_in[8];
    const float* Woff2 = (const float*)d_in[9];
    const float* rpb   = (const float*)d_in[10];
    const float* Wout  = (const float*)d_in[11];
    const float* bout  = (const float*)d_in[12];
    float* out = (float*)d_out;

    char* wsb = (char*)d_ws;
    float* qbuf = (float*)wsb;                                          // 128MB (q -> O in place)
    unsigned short* khi = (unsigned short*)(wsb + (size_t)NPIX * 64 * 4);
    unsigned short* klo = khi + (size_t)NPIX * 64;
    unsigned short* vhi = klo + (size_t)NPIX * 64;
    unsigned short* vlo = vhi + (size_t)NPIX * 64;
    float* coords = (float*)(vlo + (size_t)NPIX * 64);                  // 4MB
    float* wcomb  = coords + (size_t)NPIX * 2;                          // 3200
    float* bcomb  = wcomb + 3200;                                       // 2
    float* bcat   = bcomb + 2;                                          // 128
    unsigned short* wcath = (unsigned short*)(bcat + 128);              // 8192
    unsigned short* wcatl = wcath + 8192;
    unsigned short* wkvh  = wcatl + 8192;                               // 8192
    unsigned short* wkvl  = wkvh + 8192;
    unsigned short* wouth = wkvl + 8192;                                // 4096
    unsigned short* woutl = wouth + 4096;
    float* proj = (float*)khi;   // 100MB scratch (khi+klo region), consumed before k written

    build_wcomb_kernel<<<13, 256, 0, stream>>>(Woff1, boff1, Woff2, wcomb, bcomb);
    build_wcat_kernel<<<33, 256, 0, stream>>>(Wq, bq, wcomb, wcath, wcatl, bcat);
    build_wfixed_kernel<<<48, 256, 0, stream>>>(Wk, Wv, Wout, wkvh, wkvl, wouth, woutl);
    convqp_kernel<<<NPIX / 64, 256, 0, stream>>>(x, wcath, wcatl, bcat, qbuf, proj);
    offset_gather_kernel<<<dim3(256, 8), 256, 0, stream>>>(proj, bcomb, (float2*)coords);
    sample_kv_kernel<<<NPIX / 64, 256, 0, stream>>>(x, (const float2*)coords, wkvh, wkvl,
                                                    bk, bv, rpb, khi, klo, vhi, vlo);
    vtrans_kernel<<<5120, 256, 0, stream>>>(vhi, vlo);
    attn_mfma_kernel<<<2048, 512, 0, stream>>>(qbuf, khi, klo, vhi, vlo);
    convout_kernel<<<NPIX / 64, 256, 0, stream>>>(qbuf, wouth, woutl, bout, out);
}

// Round 7
// 632.721 us; speedup vs baseline: 1.2550x; 1.2550x over previous
//
#include <hip/hip_runtime.h>
#include <math.h>

#define NPIX 524288   // 8*256*256

typedef __attribute__((ext_vector_type(8))) short short8b;
typedef __attribute__((ext_vector_type(4))) float f32x4;
#define MFMA16 __builtin_amdgcn_mfma_f32_16x16x32_bf16

__device__ inline unsigned short bf16_rn(float x) {
    unsigned u = __float_as_uint(x);
    unsigned r = (u + 0x7FFFu + ((u >> 16) & 1u)) >> 16;
    return (unsigned short)r;
}
__device__ inline float bf16_f(unsigned short h) {
    return __uint_as_float(((unsigned)h) << 16);
}
__device__ inline void split4(float a, float b, float c, float d, ushort4& hv, ushort4& lv) {
    hv.x = bf16_rn(a); lv.x = bf16_rn(a - bf16_f(hv.x));
    hv.y = bf16_rn(b); lv.y = bf16_rn(b - bf16_f(hv.y));
    hv.z = bf16_rn(c); lv.z = bf16_rn(c - bf16_f(hv.z));
    hv.w = bf16_rn(d); lv.w = bf16_rn(d - bf16_f(hv.w));
}

// ---------- kernel 1a: collapse offset head: Wcomb[p][cin][tap] = sum_c Woff2[p,c]*Woff1[c,cin,tap]
__global__ void build_wcomb_kernel(const float* __restrict__ Woff1,
                                   const float* __restrict__ boff1,
                                   const float* __restrict__ Woff2,
                                   float* __restrict__ wcomb,
                                   float* __restrict__ bcomb) {
    int idx = blockIdx.x * 256 + threadIdx.x;
    if (idx < 2 * 64 * 25) {
        int p = idx / 1600;
        int rest = idx - p * 1600;
        float s = 0.f;
        for (int cm = 0; cm < 64; ++cm)
            s += Woff2[p * 64 + cm] * Woff1[cm * 1600 + rest];
        wcomb[idx] = s;
    }
    if (idx < 2) {
        float s = 0.f;
        for (int cm = 0; cm < 64; ++cm) s += Woff2[idx * 64 + cm] * boff1[cm];
        bcomb[idx] = s;
    }
}

// ---------- kernel 1b: Wcat[128][64] = [Wq ; Wproj@Wq ; 0] as bf16 hi/lo planes + fp32 bcat
__global__ void build_wcat_kernel(const float* __restrict__ Wq, const float* __restrict__ bq,
                                  const float* __restrict__ wcomb,
                                  unsigned short* __restrict__ wcath,
                                  unsigned short* __restrict__ wcatl,
                                  float* __restrict__ bcat) {
    int idx = blockIdx.x * 256 + threadIdx.x;
    if (idx < 8192) {
        int r = idx >> 6, c = idx & 63;
        float v = 0.f;
        if (r < 64) v = Wq[r * 64 + c];
        else if (r < 114) {
            int ch = r - 64, p = ch / 25, tap = ch % 25;
            for (int cin = 0; cin < 64; ++cin)
                v += wcomb[p * 1600 + cin * 25 + tap] * Wq[cin * 64 + c];
        }
        unsigned short hh = bf16_rn(v);
        wcath[idx] = hh;
        wcatl[idx] = bf16_rn(v - bf16_f(hh));
    }
    if (idx >= 8192 && idx < 8192 + 128) {
        int r = idx - 8192;
        float v = 0.f;
        if (r < 64) v = bq[r];
        else if (r < 114) {
            int ch = r - 64, p = ch / 25, tap = ch % 25;
            for (int cin = 0; cin < 64; ++cin)
                v += wcomb[p * 1600 + cin * 25 + tap] * bq[cin];
        }
        bcat[r] = v;
    }
}

// ---------- kernel 1c: fixed weights -> bf16 hi/lo planes (wkv rows 0..63=k, 64..127=v; wout)
__global__ void build_wfixed_kernel(const float* __restrict__ Wk, const float* __restrict__ Wv,
                                    const float* __restrict__ Wout,
                                    unsigned short* __restrict__ wkvh, unsigned short* __restrict__ wkvl,
                                    unsigned short* __restrict__ wouth, unsigned short* __restrict__ woutl) {
    int idx = blockIdx.x * 256 + threadIdx.x;
    if (idx < 8192) {
        float v = (idx < 4096) ? Wk[idx] : Wv[idx - 4096];
        unsigned short hh = bf16_rn(v);
        wkvh[idx] = hh;
        wkvl[idx] = bf16_rn(v - bf16_f(hh));
    } else if (idx < 12288) {
        float v = Wout[idx - 8192];
        unsigned short hh = bf16_rn(v);
        wouth[idx - 8192] = hh;
        woutl[idx - 8192] = bf16_rn(v - bf16_f(hh));
    }
}

// ---------- kernel 2: fused q + proj conv via MFMA (M=64 pixels, N=128, K=64)
__global__ __launch_bounds__(256)
void convqp_kernel(const float* __restrict__ in, const unsigned short* __restrict__ wh,
                   const unsigned short* __restrict__ wl, const float* __restrict__ bcat,
                   float* __restrict__ qout, float* __restrict__ projout) {
    __shared__ unsigned short a_hi[64 * 72], a_lo[64 * 72];
    int t = threadIdx.x;
    int p = t & 63, w = t >> 6;
    int pix0 = blockIdx.x * 64;
    {
        const float4* src = (const float4*)(in + (size_t)(pix0 + p) * 64 + w * 16);
#pragma unroll
        for (int u4 = 0; u4 < 4; ++u4) {
            float4 v = src[u4];
            ushort4 hv, lv;
            split4(v.x, v.y, v.z, v.w, hv, lv);
            *(ushort4*)&a_hi[p * 72 + w * 16 + u4 * 4] = hv;
            *(ushort4*)&a_lo[p * 72 + w * 16 + u4 * 4] = lv;
        }
    }
    __syncthreads();
    int lrow = t & 15, lgrp = (t & 63) >> 4;
    int wc = w * 32;
    f32x4 acc[4][2];
#pragma unroll
    for (int mi = 0; mi < 4; ++mi)
#pragma unroll
        for (int nj = 0; nj < 2; ++nj) acc[mi][nj] = (f32x4){0.f, 0.f, 0.f, 0.f};
#pragma unroll
    for (int dk = 0; dk < 2; ++dk) {
        int k0 = dk * 32 + lgrp * 8;
        short8b bh[2], bl[2];
#pragma unroll
        for (int nj = 0; nj < 2; ++nj) {
            int c = wc + nj * 16 + lrow;
            bh[nj] = *(const short8b*)(wh + c * 64 + k0);
            bl[nj] = *(const short8b*)(wl + c * 64 + k0);
        }
#pragma unroll
        for (int mi = 0; mi < 4; ++mi) {
            int r = mi * 16 + lrow;
            short8b ah = *(short8b*)&a_hi[r * 72 + k0];
            short8b al = *(short8b*)&a_lo[r * 72 + k0];
#pragma unroll
            for (int nj = 0; nj < 2; ++nj) {
                acc[mi][nj] = MFMA16(ah, bh[nj], acc[mi][nj], 0, 0, 0);
                acc[mi][nj] = MFMA16(ah, bl[nj], acc[mi][nj], 0, 0, 0);
                acc[mi][nj] = MFMA16(al, bh[nj], acc[mi][nj], 0, 0, 0);
            }
        }
    }
    int b = pix0 >> 16, hw0 = pix0 & 65535;
#pragma unroll
    for (int nj = 0; nj < 2; ++nj) {
        int c = wc + nj * 16 + lrow;
        if (c < 114) {
            float bias = bcat[c];
            float* dst = (c < 64) ? (qout + (((size_t)(b * 64 + c)) << 16) + hw0)
                                  : (projout + (((size_t)(b * 50 + (c - 64))) << 16) + hw0);
#pragma unroll
            for (int mi = 0; mi < 4; ++mi) {
                float4 o;
                o.x = acc[mi][nj][0] + bias;
                o.y = acc[mi][nj][1] + bias;
                o.z = acc[mi][nj][2] + bias;
                o.w = acc[mi][nj][3] + bias;
                *(float4*)(dst + mi * 16 + lgrp * 4) = o;
            }
        }
    }
}

// ---------- kernel 3: offset via 25-tap shift-add over proj planes -> sample coords
__global__ __launch_bounds__(256)
void offset_gather_kernel(const float* __restrict__ proj, const float* __restrict__ bcomb,
                          float2* __restrict__ coords) {
    int x = threadIdx.x, y = blockIdx.x, b = blockIdx.y;
    const float* pb = proj + (((size_t)b * 50) << 16);
    float a0 = bcomb[0], a1 = bcomb[1];
#pragma unroll
    for (int ky = 0; ky < 5; ++ky) {
        int yy = y + ky - 2;
        if (yy < 0 || yy >= 256) continue;
#pragma unroll
        for (int kx = 0; kx < 5; ++kx) {
            int xx = x + kx - 2;
            if (xx < 0 || xx >= 256) continue;
            int tap = ky * 5 + kx;
            size_t off = (size_t)yy * 256 + xx;
            a0 += pb[((size_t)tap << 16) + off];
            a1 += pb[((size_t)(25 + tap) << 16) + off];
        }
    }
    float ox = tanhf(a0) * 5.f, oy = tanhf(a1) * 5.f;
    float vgx = (float)x + ox, vgy = (float)y + oy;
    float ix = vgx * (256.f / 255.f) - 0.5f;
    float iy = vgy * (256.f / 255.f) - 0.5f;
    coords[(((size_t)b) << 16) + y * 256 + x] = make_float2(ix, iy);
}

// ---------- kernel 4: bilinear sample + k/v convs via MFMA, emit bf16 hi/lo planes
__global__ __launch_bounds__(256)
void sample_kv_kernel(const float* __restrict__ x, const float2* __restrict__ coords,
                      const unsigned short* __restrict__ wh, const unsigned short* __restrict__ wl,
                      const float* __restrict__ bk, const float* __restrict__ bv,
                      const float* __restrict__ rpb,
                      unsigned short* __restrict__ khi, unsigned short* __restrict__ klo,
                      unsigned short* __restrict__ vhi, unsigned short* __restrict__ vlo) {
    __shared__ unsigned short a_hi[64 * 72], a_lo[64 * 72];
    int t = threadIdx.x;
    int p = t & 63, w = t >> 6;
    int pix0 = blockIdx.x * 64;
    int pix = pix0 + p;
    int b = pix0 >> 16, hw0 = pix0 & 65535, h = hw0 >> 8;
    {
        float2 cc = coords[pix];
        float ix0f = floorf(cc.x), iy0f = floorf(cc.y);
        float wx1 = cc.x - ix0f, wy1 = cc.y - iy0f;
        float wx0 = 1.f - wx1, wy0 = 1.f - wy1;
        int ix0 = (int)ix0f, iy0 = (int)iy0f;
        float s[16];
#pragma unroll
        for (int u = 0; u < 16; ++u) s[u] = 0.f;
        const float* xb = x + (((size_t)b) << 16) * 64 + w * 16;
        int cxs[4] = {ix0, ix0 + 1, ix0, ix0 + 1};
        int cys[4] = {iy0, iy0, iy0 + 1, iy0 + 1};
        float ws4[4] = {wx0 * wy0, wx1 * wy0, wx0 * wy1, wx1 * wy1};
#pragma unroll
        for (int cr = 0; cr < 4; ++cr) {
            int cx = cxs[cr], cy = cys[cr];
            if (cx >= 0 && cx < 256 && cy >= 0 && cy < 256) {
                float wgt = ws4[cr];
                const float4* sp = (const float4*)(xb + ((size_t)(cy * 256 + cx) << 6));
#pragma unroll
                for (int q4 = 0; q4 < 4; ++q4) {
                    float4 v = sp[q4];
                    s[4 * q4] += wgt * v.x; s[4 * q4 + 1] += wgt * v.y;
                    s[4 * q4 + 2] += wgt * v.z; s[4 * q4 + 3] += wgt * v.w;
                }
            }
        }
#pragma unroll
        for (int u4 = 0; u4 < 4; ++u4) {
            ushort4 hv, lv;
            split4(s[u4 * 4], s[u4 * 4 + 1], s[u4 * 4 + 2], s[u4 * 4 + 3], hv, lv);
            *(ushort4*)&a_hi[p * 72 + w * 16 + u4 * 4] = hv;
            *(ushort4*)&a_lo[p * 72 + w * 16 + u4 * 4] = lv;
        }
    }
    __syncthreads();
    int lrow = t & 15, lgrp = (t & 63) >> 4;
    int wc = w * 32;
    f32x4 acc[4][2];
#pragma unroll
    for (int mi = 0; mi < 4; ++mi)
#pragma unroll
        for (int nj = 0; nj < 2; ++nj) acc[mi][nj] = (f32x4){0.f, 0.f, 0.f, 0.f};
#pragma unroll
    for (int dk = 0; dk < 2; ++dk) {
        int k0 = dk * 32 + lgrp * 8;
        short8b bh[2], bl[2];
#pragma unroll
        for (int nj = 0; nj < 2; ++nj) {
            int c = wc + nj * 16 + lrow;
            bh[nj] = *(const short8b*)(wh + c * 64 + k0);
            bl[nj] = *(const short8b*)(wl + c * 64 + k0);
        }
#pragma unroll
        for (int mi = 0; mi < 4; ++mi) {
            int r = mi * 16 + lrow;
            short8b ah = *(short8b*)&a_hi[r * 72 + k0];
            short8b al = *(short8b*)&a_lo[r * 72 + k0];
#pragma unroll
            for (int nj = 0; nj < 2; ++nj) {
                acc[mi][nj] = MFMA16(ah, bh[nj], acc[mi][nj], 0, 0, 0);
                acc[mi][nj] = MFMA16(ah, bl[nj], acc[mi][nj], 0, 0, 0);
                acc[mi][nj] = MFMA16(al, bh[nj], acc[mi][nj], 0, 0, 0);
            }
        }
    }
#pragma unroll
    for (int nj = 0; nj < 2; ++nj) {
        int c = wc + nj * 16 + lrow;
        float bias;
        unsigned short *dh, *dl;
        if (c < 64) { bias = bk[c]; dh = khi; dl = klo; }
        else        { bias = bv[c - 64] + rpb[(c - 64) * 256 + h]; dh = vhi; dl = vlo; }
        size_t o = (((size_t)(b * 64 + (c & 63))) << 16) + hw0;
#pragma unroll
        for (int mi = 0; mi < 4; ++mi) {
            float v0 = acc[mi][nj][0] + bias;
            float v1 = acc[mi][nj][1] + bias;
            float v2 = acc[mi][nj][2] + bias;
            float v3 = acc[mi][nj][3] + bias;
            ushort4 hv, lv;
            split4(v0, v1, v2, v3, hv, lv);
            *(ushort4*)(dh + o + mi * 16 + lgrp * 4) = hv;
            *(ushort4*)(dl + o + mi * 16 + lgrp * 4) = lv;
        }
    }
}

// ---------- kernel 4b: in-place paired-tile transpose of v hi/lo planes ([head][j][d] -> [head][d][j])
__global__ __launch_bounds__(256)
void vtrans_kernel(unsigned short* __restrict__ vhi, unsigned short* __restrict__ vlo) {
    __shared__ unsigned short T1[64][72];
    __shared__ unsigned short T2[64][72];
    const int ti_tab[10] = {0, 0, 0, 0, 1, 1, 1, 2, 2, 3};
    const int tj_tab[10] = {0, 1, 2, 3, 1, 2, 3, 2, 3, 3};
    int head = blockIdx.x / 10, pidx = blockIdx.x - head * 10;
    int ti = ti_tab[pidx], tj = tj_tab[pidx];
    int t = threadIdx.x;
    int r = t >> 2, cs = (t & 3) * 16;
    bool diag = (ti == tj);
#pragma unroll
    for (int pl = 0; pl < 2; ++pl) {
        unsigned short* base = (pl ? vlo : vhi) + ((size_t)head << 16);
        *(short8b*)&T1[r][cs]     = *(const short8b*)(base + (size_t)(ti * 64 + r) * 256 + tj * 64 + cs);
        *(short8b*)&T1[r][cs + 8] = *(const short8b*)(base + (size_t)(ti * 64 + r) * 256 + tj * 64 + cs + 8);
        if (!diag) {
            *(short8b*)&T2[r][cs]     = *(const short8b*)(base + (size_t)(tj * 64 + r) * 256 + ti * 64 + cs);
            *(short8b*)&T2[r][cs + 8] = *(const short8b*)(base + (size_t)(tj * 64 + r) * 256 + ti * 64 + cs + 8);
        }
        __syncthreads();
        {
            short8b o0, o1;
#pragma unroll
            for (int u = 0; u < 8; ++u) { o0[u] = (short)T1[cs + u][r]; o1[u] = (short)T1[cs + 8 + u][r]; }
            *(short8b*)(base + (size_t)(tj * 64 + r) * 256 + ti * 64 + cs) = o0;
            *(short8b*)(base + (size_t)(tj * 64 + r) * 256 + ti * 64 + cs + 8) = o1;
            if (!diag) {
#pragma unroll
                for (int u = 0; u < 8; ++u) { o0[u] = (short)T2[cs + u][r]; o1[u] = (short)T2[cs + 8 + u][r]; }
                *(short8b*)(base + (size_t)(ti * 64 + r) * 256 + tj * 64 + cs) = o0;
                *(short8b*)(base + (size_t)(ti * 64 + r) * 256 + tj * 64 + cs + 8) = o1;
            }
        }
        __syncthreads();
    }
}

// ---------- kernel 5: MFMA attention; depth-2 pipeline with NAMED register buffers (no arrays)
#define KLOAD(B, S) do { \
    size_t go0 = (size_t)(wc + lrow) * 256 + (S) * 32 + lgrp * 8; \
    size_t go1 = go0 + 16 * 256; \
    B##h0 = *(const short8b*)(kh + go0); \
    B##h1 = *(const short8b*)(kh + go1); \
    B##l0 = *(const short8b*)(kl + go0); \
    B##l1 = *(const short8b*)(kl + go1); \
} while (0)

#define KSTEP(B, S) do { \
    int k0_ = (S) * 32 + lgrp * 8; \
    __builtin_amdgcn_s_setprio(1); \
    _Pragma("unroll") \
    for (int mi = 0; mi < 4; ++mi) { \
        short8b ah = *(short8b*)&qhi[(mi * 16 + lrow) * 264 + k0_]; \
        short8b al = *(short8b*)&qlo[(mi * 16 + lrow) * 264 + k0_]; \
        acc[mi][0] = MFMA16(ah, B##h0, acc[mi][0], 0, 0, 0); \
        acc[mi][0] = MFMA16(ah, B##l0, acc[mi][0], 0, 0, 0); \
        acc[mi][0] = MFMA16(al, B##h0, acc[mi][0], 0, 0, 0); \
        acc[mi][1] = MFMA16(ah, B##h1, acc[mi][1], 0, 0, 0); \
        acc[mi][1] = MFMA16(ah, B##l1, acc[mi][1], 0, 0, 0); \
        acc[mi][1] = MFMA16(al, B##h1, acc[mi][1], 0, 0, 0); \
    } \
    __builtin_amdgcn_s_setprio(0); \
} while (0)

#define VLOAD(B, S) do { \
    size_t go0 = (size_t)(wc + lrow) * 256 + (S) * 32 + lgrp * 8; \
    size_t go1 = go0 + 16 * 256; \
    B##h0 = *(const short8b*)(vth + go0); \
    B##h1 = *(const short8b*)(vth + go1); \
    B##l0 = *(const short8b*)(vtl + go0); \
    B##l1 = *(const short8b*)(vtl + go1); \
} while (0)

#define VSTEP(B, S) do { \
    int j0_ = (S) * 32 + lgrp * 8; \
    __builtin_amdgcn_s_setprio(1); \
    _Pragma("unroll") \
    for (int mi = 0; mi < 4; ++mi) { \
        short8b pa = *(short8b*)&phi[(mi * 16 + lrow) * 264 + j0_]; \
        short8b pb = *(short8b*)&plo[(mi * 16 + lrow) * 264 + j0_]; \
        acc[mi][0] = MFMA16(pa, B##h0, acc[mi][0], 0, 0, 0); \
        acc[mi][0] = MFMA16(pa, B##l0, acc[mi][0], 0, 0, 0); \
        acc[mi][0] = MFMA16(pb, B##h0, acc[mi][0], 0, 0, 0); \
        acc[mi][1] = MFMA16(pa, B##h1, acc[mi][1], 0, 0, 0); \
        acc[mi][1] = MFMA16(pa, B##l1, acc[mi][1], 0, 0, 0); \
        acc[mi][1] = MFMA16(pb, B##h1, acc[mi][1], 0, 0, 0); \
    } \
    __builtin_amdgcn_s_setprio(0); \
} while (0)

__global__ __launch_bounds__(512, 4)
void attn_mfma_kernel(float* __restrict__ qo,
                      const unsigned short* __restrict__ khig, const unsigned short* __restrict__ klog,
                      const unsigned short* __restrict__ vthig, const unsigned short* __restrict__ vtlog) {
    __shared__ char sm[71680];
    unsigned short* qhi = (unsigned short*)sm;
    unsigned short* qlo = (unsigned short*)(sm + 33792);
    unsigned short* phi = (unsigned short*)sm;
    unsigned short* plo = (unsigned short*)(sm + 33792);
    float* ost = (float*)sm;
    float* redm = (float*)(sm + 67584);
    float* reds = (float*)(sm + 69632);

    int t = threadIdx.x;
    int lane = t & 63, w = t >> 6;
    int lrow = lane & 15, lgrp = lane >> 4;
    int wc = w * 32;

    int bid = blockIdx.x;
    int xcd = bid & 7, r = bid >> 3;
    int head = xcd * 64 + (r >> 2), rt = r & 3;
    float* qg = qo + ((size_t)head << 16) + rt * 64 * 256;
    const unsigned short* kh = khig + ((size_t)head << 16);
    const unsigned short* kl = klog + ((size_t)head << 16);
    const unsigned short* vth = vthig + ((size_t)head << 16);
    const unsigned short* vtl = vtlog + ((size_t)head << 16);

    // three named k-fragment buffers (16 VGPRs each)
    short8b kAh0, kAh1, kAl0, kAl1;
    short8b kBh0, kBh1, kBl0, kBl1;
    short8b kCh0, kCh1, kCl0, kCl1;

    // prologue: issue steps 0,1 BEFORE q staging (latency hides under staging+barrier)
    KLOAD(kA, 0);
    KLOAD(kB, 1);

    // ---- stage q 64x256 fp32 -> bf16 hi/lo in LDS
    {
        int row = t >> 3, cb = (t & 7) * 32;
        const float* qrow = qg + row * 256 + cb;
#pragma unroll
        for (int q4 = 0; q4 < 8; ++q4) {
            float4 v = *(const float4*)(qrow + q4 * 4);
            ushort4 hv, lv;
            split4(v.x, v.y, v.z, v.w, hv, lv);
            *(ushort4*)&qhi[row * 264 + cb + q4 * 4] = hv;
            *(ushort4*)&qlo[row * 264 + cb + q4 * 4] = lv;
        }
    }
    __syncthreads();

    f32x4 acc[4][2];
#pragma unroll
    for (int mi = 0; mi < 4; ++mi)
#pragma unroll
        for (int nj = 0; nj < 2; ++nj) acc[mi][nj] = (f32x4){0.f, 0.f, 0.f, 0.f};

    // ---- phase 1: S = q k^T, 8 steps, depth-2, hand-rotated named buffers
    KLOAD(kC, 2); KSTEP(kA, 0);
    KLOAD(kA, 3); KSTEP(kB, 1);
    KLOAD(kB, 4); KSTEP(kC, 2);
    KLOAD(kC, 5); KSTEP(kA, 3);
    KLOAD(kA, 6); KSTEP(kB, 4);
    KLOAD(kB, 7); KSTEP(kC, 5);
    KSTEP(kA, 6);
    KSTEP(kB, 7);

    // v buffers reuse the same rotation; issue jc=0,1 now (hides under softmax)
    short8b vAh0, vAh1, vAl0, vAl1;
    short8b vBh0, vBh1, vBl0, vBl1;
    short8b vCh0, vCh1, vCl0, vCl1;
    VLOAD(vA, 0);
    VLOAD(vB, 1);

    // ---- phase 2: softmax
#pragma unroll
    for (int mi = 0; mi < 4; ++mi)
#pragma unroll
        for (int nj = 0; nj < 2; ++nj) acc[mi][nj] *= 0.125f;

    float mx[4][4];
#pragma unroll
    for (int mi = 0; mi < 4; ++mi)
#pragma unroll
        for (int rr = 0; rr < 4; ++rr) {
            float m = fmaxf(acc[mi][0][rr], acc[mi][1][rr]);
            m = fmaxf(m, __shfl_xor(m, 1));
            m = fmaxf(m, __shfl_xor(m, 2));
            m = fmaxf(m, __shfl_xor(m, 4));
            m = fmaxf(m, __shfl_xor(m, 8));
            mx[mi][rr] = m;
        }
    if (lrow == 0) {
#pragma unroll
        for (int mi = 0; mi < 4; ++mi)
#pragma unroll
            for (int rr = 0; rr < 4; ++rr)
                redm[w * 64 + mi * 16 + lgrp * 4 + rr] = mx[mi][rr];
    }
    __syncthreads();   // redm ready; all q-frag reads done -> phi/plo may overwrite
#pragma unroll
    for (int mi = 0; mi < 4; ++mi)
#pragma unroll
        for (int rr = 0; rr < 4; ++rr) {
            int row = mi * 16 + lgrp * 4 + rr;
            float m = redm[row];
#pragma unroll
            for (int ww = 1; ww < 8; ++ww) m = fmaxf(m, redm[ww * 64 + row]);
            float p0 = __expf(acc[mi][0][rr] - m);
            float p1 = __expf(acc[mi][1][rr] - m);
            unsigned short h0 = bf16_rn(p0), h1 = bf16_rn(p1);
            phi[row * 264 + wc + lrow] = h0;
            phi[row * 264 + wc + 16 + lrow] = h1;
            plo[row * 264 + wc + lrow] = bf16_rn(p0 - bf16_f(h0));
            plo[row * 264 + wc + 16 + lrow] = bf16_rn(p1 - bf16_f(h1));
            float ls = p0 + p1;
            ls += __shfl_xor(ls, 1);
            ls += __shfl_xor(ls, 2);
            ls += __shfl_xor(ls, 4);
            ls += __shfl_xor(ls, 8);
            if (lrow == 0) reds[w * 64 + row] = ls;
        }
    __syncthreads();   // phi/plo + reds ready

    // ---- phase 3: O = P V, 8 steps, depth-2, named buffers (invl deferred to epilogue)
#pragma unroll
    for (int mi = 0; mi < 4; ++mi)
#pragma unroll
        for (int nd = 0; nd < 2; ++nd) acc[mi][nd] = (f32x4){0.f, 0.f, 0.f, 0.f};

    VLOAD(vC, 2); VSTEP(vA, 0);
    VLOAD(vA, 3); VSTEP(vB, 1);
    VLOAD(vB, 4); VSTEP(vC, 2);
    VLOAD(vC, 5); VSTEP(vA, 3);
    VLOAD(vA, 6); VSTEP(vB, 4);
    VLOAD(vB, 7); VSTEP(vC, 5);
    VSTEP(vA, 6);
    VSTEP(vB, 7);
    __syncthreads();   // all phi/plo reads done -> ost may overwrite

    // ---- epilogue: compute 1/l from reds (still resident above ost), scale, store
    float invl[4][4];
#pragma unroll
    for (int mi = 0; mi < 4; ++mi)
#pragma unroll
        for (int rr = 0; rr < 4; ++rr) {
            int row = mi * 16 + lgrp * 4 + rr;
            float l = 0.f;
#pragma unroll
            for (int ww = 0; ww < 8; ++ww) l += reds[ww * 64 + row];
            invl[mi][rr] = 1.f / l;
        }
#pragma unroll
    for (int mi = 0; mi < 4; ++mi)
#pragma unroll
        for (int nd = 0; nd < 2; ++nd)
#pragma unroll
            for (int rr = 0; rr < 4; ++rr)
                ost[(mi * 16 + lgrp * 4 + rr) * 260 + wc + nd * 16 + lrow] =
                    acc[mi][nd][rr] * invl[mi][rr];
    __syncthreads();
#pragma unroll
    for (int it = 0; it < 8; ++it) {
        int id = it * 512 + t;
        int row = id >> 6, col4 = (id & 63) * 4;
        float4 vv = *(float4*)&ost[row * 260 + col4];
        *(float4*)(qg + row * 256 + col4) = vv;
    }
}

// ---------- kernel 6: final 1x1 conv via MFMA (flat [pix][64] in/out, M=64, N=64, K=64)
__global__ __launch_bounds__(256)
void convout_kernel(const float* __restrict__ in, const unsigned short* __restrict__ wh,
                    const unsigned short* __restrict__ wl, const float* __restrict__ bias,
                    float* __restrict__ out) {
    __shared__ unsigned short a_hi[64 * 72], a_lo[64 * 72];
    int t = threadIdx.x;
    int p = t & 63, w = t >> 6;
    int pix0 = blockIdx.x * 64;
    {
        const float4* src = (const float4*)(in + (size_t)(pix0 + p) * 64 + w * 16);
#pragma unroll
        for (int u4 = 0; u4 < 4; ++u4) {
            float4 v = src[u4];
            ushort4 hv, lv;
            split4(v.x, v.y, v.z, v.w, hv, lv);
            *(ushort4*)&a_hi[p * 72 + w * 16 + u4 * 4] = hv;
            *(ushort4*)&a_lo[p * 72 + w * 16 + u4 * 4] = lv;
        }
    }
    __syncthreads();
    int lrow = t & 15, lgrp = (t & 63) >> 4;
    int c = w * 16 + lrow;
    f32x4 acc[4];
#pragma unroll
    for (int mi = 0; mi < 4; ++mi) acc[mi] = (f32x4){0.f, 0.f, 0.f, 0.f};
#pragma unroll
    for (int dk = 0; dk < 2; ++dk) {
        int k0 = dk * 32 + lgrp * 8;
        short8b bh = *(const short8b*)(wh + c * 64 + k0);
        short8b bl = *(const short8b*)(wl + c * 64 + k0);
#pragma unroll
        for (int mi = 0; mi < 4; ++mi) {
            int r = mi * 16 + lrow;
            short8b ah = *(short8b*)&a_hi[r * 72 + k0];
            short8b al = *(short8b*)&a_lo[r * 72 + k0];
            acc[mi] = MFMA16(ah, bh, acc[mi], 0, 0, 0);
            acc[mi] = MFMA16(ah, bl, acc[mi], 0, 0, 0);
            acc[mi] = MFMA16(al, bh, acc[mi], 0, 0, 0);
        }
    }
    float bb = bias[c];
#pragma unroll
    for (int mi = 0; mi < 4; ++mi) {
        int px0 = pix0 + mi * 16 + lgrp * 4;
#pragma unroll
        for (int rr = 0; rr < 4; ++rr)
            out[(size_t)(px0 + rr) * 64 + c] = acc[mi][rr] + bb;
    }
}

extern "C" void kernel_launch(void* const* d_in, const int* in_sizes, int n_in,
                              void* d_out, int out_size, void* d_ws, size_t ws_size,
                              hipStream_t stream) {
    const float* x     = (const float*)d_in[0];
    const float* Wq    = (const float*)d_in[1];
    const float* bq    = (const float*)d_in[2];
    const float* Wk    = (const float*)d_in[3];
    const float* bk    = (const float*)d_in[4];
    const float* Wv    = (const float*)d_in[5];
    const float* bv    = (const float*)d_in[6];
    const float* Woff1 = (const float*)d_in[7];
    const float* boff1 = (const float*)d_in[8];
    const float* Woff2 = (const float*)d_in[9];
    const float* rpb   = (const float*)d_in[10];
    const float* Wout  = (const float*)d_in[11];
    const float* bout  = (const float*)d_in[12];
    float* out = (float*)d_out;

    char* wsb = (char*)d_ws;
    float* qbuf = (float*)wsb;                                          // 128MB (q -> O in place)
    unsigned short* khi = (unsigned short*)(wsb + (size_t)NPIX * 64 * 4);
    unsigned short* klo = khi + (size_t)NPIX * 64;
    unsigned short* vhi = klo + (size_t)NPIX * 64;
    unsigned short* vlo = vhi + (size_t)NPIX * 64;
    float* coords = (float*)(vlo + (size_t)NPIX * 64);                  // 4MB
    float* wcomb  = coords + (size_t)NPIX * 2;                          // 3200
    float* bcomb  = wcomb + 3200;                                       // 2
    float* bcat   = bcomb + 2;                                          // 128
    unsigned short* wcath = (unsigned short*)(bcat + 128);              // 8192
    unsigned short* wcatl = wcath + 8192;
    unsigned short* wkvh  = wcatl + 8192;                               // 8192
    unsigned short* wkvl  = wkvh + 8192;
    unsigned short* wouth = wkvl + 8192;                                // 4096
    unsigned short* woutl = wouth + 4096;
    float* proj = (float*)khi;   // 100MB scratch (khi+klo region), consumed before k written

    build_wcomb_kernel<<<13, 256, 0, stream>>>(Woff1, boff1, Woff2, wcomb, bcomb);
    build_wcat_kernel<<<33, 256, 0, stream>>>(Wq, bq, wcomb, wcath, wcatl, bcat);
    build_wfixed_kernel<<<48, 256, 0, stream>>>(Wk, Wv, Wout, wkvh, wkvl, wouth, woutl);
    convqp_kernel<<<NPIX / 64, 256, 0, stream>>>(x, wcath, wcatl, bcat, qbuf, proj);
    offset_gather_kernel<<<dim3(256, 8), 256, 0, stream>>>(proj, bcomb, (float2*)coords);
    sample_kv_kernel<<<NPIX / 64, 256, 0, stream>>>(x, (const float2*)coords, wkvh, wkvl,
                                                    bk, bv, rpb, khi, klo, vhi, vlo);
    vtrans_kernel<<<5120, 256, 0, stream>>>(vhi, vlo);
    attn_mfma_kernel<<<2048, 512, 0, stream>>>(qbuf, khi, klo, vhi, vlo);
    convout_kernel<<<NPIX / 64, 256, 0, stream>>>(qbuf, wouth, woutl, bout, out);
}